// Round 6
// baseline (11910.995 us; speedup 1.0000x reference)
//
#include <hip/hip_runtime.h>

// 2-layer LSTM (H=50) + FC head. Transposed-MFMA fp16.
// R19 = TWO SYNC DOMAINS, SAME TOTAL WORK (the R15 mechanism without 2x work):
//   grid 512: blocks 0..255 = A-team (L1 recurrence, 8 waves, own barrier),
//   blocks 256..511 = B-team (L2 + FC, 8 waves, own barrier). A-blocks
//   dispatch first -> each CU hosts 1 A + 1 B = 16 waves (as R13), but each
//   team's 512 barriers no longer freeze the other team's waves, which fill
//   the convoy bubbles. R15 measured 81% issue efficiency for two independent
//   domains (vs 53% single-domain) -- here at R13's issue budget.
//   h1 handoff: 16-deep global ring (2KB/step/pair, LLC-resident, 8MB ws):
//     - A: nontemporal ring stores; flag fA = completed phases, agent-scope
//       RELEASE by tid0 after __syncthreads (barrier drains all vmcnt).
//     - B: prefetches h1[t+1] ONE PHASE EARLY (latency hidden under compute);
//       ring reads = agent-scope relaxed u64 atomics (bypass stale L1/L2 --
//       correct under ANY XCD placement, G16); flag polls use CACHED progress
//       (1 real atomic per ~16 phases; s_sleep in rare spins) -- kills R18's
//       spin cost. B never waits in steady state; A paced with 16-ph cushion.
//     - flags memset to 0 per launch (hipMemsetAsync on stream, graph-safe);
//       count semantics => 0 = clean start, stale-run-proof.
//   Deadlock-free: A waits fB >= p-15 (B at most 15 behind A impossible while
//   A leads); B waits fA >= t+2 (A leads). Mutual progress guaranteed.
// Cell: R14 shared-reciprocal (7 trans). Weights in regs; h frag layout
// (chunk (kt*4+qh)*16+m); gate rows permuted p=4j+g; x/bias ride k=50/51.

#define HID 50
#define SEQ 512
#define NB 16
#define NTHREADS 512      // per block; grid = 512 (256 A + 256 B)
#define XP 516
#define RING_D 16
#define RING_SLOT 2048                      // bytes per step (128 chunks x 16B)
#define NPAIR 256
#define WS_RING_BYTES ((size_t)NPAIR * RING_D * RING_SLOT)   // 8 MiB
#define WS_BYTES (WS_RING_BYTES + (size_t)NPAIR * 256)

typedef _Float16 f16x8 __attribute__((ext_vector_type(8)));
typedef float    f32x4 __attribute__((ext_vector_type(4)));
typedef unsigned long long u64;

#define LOG2E 1.44269504f

__device__ __forceinline__ float lstm_cell(const f32x4 g, float& c) {
    const float ei = __builtin_amdgcn_exp2f(g[0]);
    const float ef = __builtin_amdgcn_exp2f(g[1]);
    const float eg = __builtin_amdgcn_exp2f(g[2]);
    const float eo = __builtin_amdgcn_exp2f(g[3]);
    const float A  = ei + 1.0f;
    const float F  = ef + 1.0f;
    const float G  = eg + 1.0f;
    const float AG  = A * G;
    const float den = AG * F;
    const float num = __builtin_fmaf(eg - 1.0f, F, c * AG);
    c = num * __builtin_amdgcn_rcpf(den);           // c' = f*c + i*tanh(xg)
    float z = c * (2.0f * LOG2E);
    z = __builtin_fminf(z, 100.0f);
    const float ec = __builtin_amdgcn_exp2f(z);
    return (ec - 1.0f) *
           __builtin_amdgcn_rcpf((eo + 1.0f) * (ec + 1.0f));  // o*tanh(c')
}

union HQ { u64 q[2]; f16x8 h; };

__global__ __launch_bounds__(NTHREADS)
void lstm2_fc_v19(const float* __restrict__ x,
                  const float* __restrict__ w_ih0,
                  const float* __restrict__ w_hh0,
                  const float* __restrict__ b_ih0,
                  const float* __restrict__ b_hh0,
                  const float* __restrict__ w_ih1,
                  const float* __restrict__ w_hh1,
                  const float* __restrict__ b_ih1,
                  const float* __restrict__ b_hh1,
                  const float* __restrict__ fc_w,
                  const float* __restrict__ fc_b,
                  float* __restrict__ out,
                  char* __restrict__ ws)
{
    __shared__ float xs[NB * XP];        // A: x for all steps (B leaves unused)
    __shared__ f16x8 hf[2][128];         // A: h1 dbuf / B: h2 dbuf

    const int tid  = threadIdx.x;
    const bool isA = (blockIdx.x < NPAIR);
    const int pair = blockIdx.x & (NPAIR - 1);
    const int b0   = pair * NB;
    const int w    = tid >> 6;
    const int l15  = tid & 15;
    const int qq   = (tid >> 4) & 3;

    char* ring = ws + (size_t)pair * (RING_D * RING_SLOT);
    int*  flg  = (int*)(ws + WS_RING_BYTES + (size_t)pair * 256);
    int* fA = flg;        // phases A has completed
    int* fB = flg + 32;   // phases B has completed (128B apart)

    if (tid < 256) { f16x8 z = {}; hf[tid >> 7][tid & 127] = z; }

    if (isA) {
        for (int idx = tid; idx < NB * 128; idx += NTHREADS) {
            const int b  = idx >> 7;
            const int t4 = idx & 127;
            *(float4*)&xs[b * XP + t4 * 4] =
                *(const float4*)&x[(size_t)(b0 + b) * SEQ + t4 * 4];
        }
        if (tid < NB) {
            const float4 z = {0.f, 0.f, 0.f, 0.f};
            *(float4*)&xs[tid * XP + 512] = z;
        }
    }
    __syncthreads();

    const int rdo = qq * 16 + l15;
    const f32x4 z4 = {0.f, 0.f, 0.f, 0.f};

    if (isA) {
        // =================== A team: L1 recurrence ===================
        if (tid < NB) {
            _Float16* e0 = (_Float16*)&hf[0][96 + tid];
            e0[2] = (_Float16)xs[tid * XP];
            e0[3] = (_Float16)1.0f;
            ((_Float16*)&hf[1][96 + tid])[3] = (_Float16)1.0f;
        }
        __syncthreads();

        // tiles: w0{0,1} w1{2,3} w2{4,5} w3{6,7} w4{8} w5{9} w6{10} w7{11,12}
        const int tA0 = (w <= 3) ? 2 * w     : (w + 4);
        const int tA1 = (w <= 3) ? 2 * w + 1 : ((w == 7) ? 12 : -1);
        const int nA  = (tA1 >= 0) ? 2 : 1;
        const int tt[2] = { tA0, (tA1 >= 0) ? tA1 : 0 };

        f16x8 wH0[2][2];
#pragma unroll
        for (int s = 0; s < 2; ++s) {
            const int  p1  = tt[s] * 16 + l15;
            const bool ok1 = (s < nA) && (p1 < 4 * HID);
            const int  n1  = ok1 ? ((p1 & 3) * HID + (p1 >> 2)) : 0;
            const float s1 = ((p1 & 3) == 2) ? (2.0f * LOG2E) : -LOG2E;
#pragma unroll
            for (int kt = 0; kt < 2; ++kt) {
                f16x8 f0;
#pragma unroll
                for (int j = 0; j < 8; ++j) {
                    const int k = kt * 32 + qq * 8 + j;
                    float v0 = 0.0f;
                    if (ok1) {
                        if (k < HID)          v0 = w_hh0[n1 * HID + k];
                        else if (k == HID)    v0 = w_ih0[n1];
                        else if (k == HID+1)  v0 = b_ih0[n1] + b_hh0[n1];
                        v0 *= s1;
                    }
                    f0[j] = (_Float16)v0;
                }
                wH0[s][kt] = f0;
            }
        }
        int wOff[2]; bool isXT[2];
#pragma unroll
        for (int s = 0; s < 2; ++s) {
            const int ju = tt[s] * 4 + qq;
            wOff[s] = ((((ju >> 5) * 4) + ((ju >> 3) & 3)) * 16 + l15) * 8 + (ju & 7);
            isXT[s] = (s < nA) && (tt[s] == 12);
        }
        const float* xrow = xs + l15 * XP;
        float c1[2] = {0.f, 0.f};
        int seenB = 0;
        _Float16* ringH = (_Float16*)ring;

#pragma unroll 2
        for (int p = 0; p < SEQ; ++p) {
            if (p >= RING_D) {                       // WAR: B consumed h1[p-16]
                const int need = p - RING_D + 1;
                while (seenB < need) {
                    seenB = __hip_atomic_load(fB, __ATOMIC_ACQUIRE,
                                              __HIP_MEMORY_SCOPE_AGENT);
                    if (seenB < need) __builtin_amdgcn_s_sleep(2);
                }
            }
            const f16x8* h1o = hf[p & 1];
            f16x8*       h1n = (f16x8*)hf[1 - (p & 1)];
            const f16x8 hb0 = h1o[rdo];
            const f16x8 hb1 = h1o[64 + rdo];
            _Float16* rs = ringH + (size_t)(p & (RING_D - 1)) * (RING_SLOT / 2);
#pragma unroll
            for (int s = 0; s < 2; ++s) if (s < nA) {
                f32x4 acc;
                acc = __builtin_amdgcn_mfma_f32_16x16x32_f16(wH0[s][0], hb0, z4,  0, 0, 0);
                acc = __builtin_amdgcn_mfma_f32_16x16x32_f16(wH0[s][1], hb1, acc, 0, 0, 0);
                const _Float16 hw = (_Float16)lstm_cell(acc, c1[s]);
                if (!isXT[s]) {
                    ((_Float16*)h1n)[wOff[s]] = hw;
                    __builtin_nontemporal_store(hw, &rs[wOff[s]]);
                } else {                               // tile 12: units 48..51
                    if (qq < 2) {
                        ((_Float16*)h1n)[wOff[s]] = hw;
                        __builtin_nontemporal_store(hw, &rs[wOff[s]]);
                    } else if (qq == 2) {              // x rider (k=50)
                        const _Float16 xv = (_Float16)xrow[p + 1];
                        ((_Float16*)h1n)[wOff[s]] = xv;
                        __builtin_nontemporal_store(xv, &rs[wOff[s]]);
                    } else {                           // 1.0 rider (k=51), ring only
                        __builtin_nontemporal_store((_Float16)1.0f, &rs[wOff[s]]);
                    }
                }
            }
            __syncthreads();   // drains every wave's vmcnt+lgkmcnt before release
            if (tid == 0)
                __hip_atomic_store(fA, p + 1, __ATOMIC_RELEASE,
                                   __HIP_MEMORY_SCOPE_AGENT);
        }
    } else {
        // =================== B team: L2 recurrence + FC ===================
        // tiles: w0{11,12} w1{0,1} w2{2,3} w3{4,5} w4{6,7} w5{8} w6{9} w7{10}
        const int tB0 = (w == 0) ? 11 : ((w <= 4) ? 2 * (w - 1) : (w + 3));
        const int tB1 = (w == 0) ? 12 : ((w <= 4) ? 2 * (w - 1) + 1 : -1);
        const int nB  = (tB1 >= 0) ? 2 : 1;
        const int tt[2] = { tB0, (tB1 >= 0) ? tB1 : 0 };

        f16x8 wI1[2][2], wH1[2][2];
#pragma unroll
        for (int s = 0; s < 2; ++s) {
            const int  p2  = tt[s] * 16 + l15;
            const bool ok2 = (s < nB) && (p2 < 4 * HID);
            const int  n2  = ok2 ? ((p2 & 3) * HID + (p2 >> 2)) : 0;
            const float s2 = ((p2 & 3) == 2) ? (2.0f * LOG2E) : -LOG2E;
#pragma unroll
            for (int kt = 0; kt < 2; ++kt) {
                f16x8 f1, f2;
#pragma unroll
                for (int j = 0; j < 8; ++j) {
                    const int k = kt * 32 + qq * 8 + j;
                    float v1 = 0.0f, v2 = 0.0f;
                    if (ok2) {
                        if (k < HID)        { v1 = w_ih1[n2 * HID + k];
                                              v2 = w_hh1[n2 * HID + k]; }
                        else if (k == HID+1)  v1 = b_ih1[n2] + b_hh1[n2];
                        v1 *= s2;
                        v2 *= s2;
                    }
                    f1[j] = (_Float16)v1;
                    f2[j] = (_Float16)v2;
                }
                wI1[s][kt] = f1;
                wH1[s][kt] = f2;
            }
        }
        int wOff[2];
#pragma unroll
        for (int s = 0; s < 2; ++s) {
            const int ju = tt[s] * 4 + qq;
            wOff[s] = ((((ju >> 5) * 4) + ((ju >> 3) & 3)) * 16 + l15) * 8 + (ju & 7);
        }
        float c2[2] = {0.f, 0.f};
        int seenA = 0;
        u64* ringQ = (u64*)ring;

        HQ P0, P1, N0, N1;
        // prologue: fetch h1[0]
        while (seenA < 1) {
            seenA = __hip_atomic_load(fA, __ATOMIC_ACQUIRE, __HIP_MEMORY_SCOPE_AGENT);
            if (seenA < 1) __builtin_amdgcn_s_sleep(2);
        }
        {
            u64* sp = ringQ;
            P0.q[0] = __hip_atomic_load(sp + rdo * 2,          __ATOMIC_RELAXED, __HIP_MEMORY_SCOPE_AGENT);
            P0.q[1] = __hip_atomic_load(sp + rdo * 2 + 1,      __ATOMIC_RELAXED, __HIP_MEMORY_SCOPE_AGENT);
            P1.q[0] = __hip_atomic_load(sp + (64+rdo) * 2,     __ATOMIC_RELAXED, __HIP_MEMORY_SCOPE_AGENT);
            P1.q[1] = __hip_atomic_load(sp + (64+rdo) * 2 + 1, __ATOMIC_RELAXED, __HIP_MEMORY_SCOPE_AGENT);
        }

#pragma unroll 2
        for (int t = 0; t < SEQ; ++t) {
            if (t < SEQ - 1) {                 // prefetch h1[t+1], one phase early
                const int need = t + 2;
                while (seenA < need) {         // cached: ~1 real poll / 16 phases
                    seenA = __hip_atomic_load(fA, __ATOMIC_ACQUIRE,
                                              __HIP_MEMORY_SCOPE_AGENT);
                    if (seenA < need) __builtin_amdgcn_s_sleep(2);
                }
                u64* sp = ringQ + (size_t)((t + 1) & (RING_D - 1)) * (RING_SLOT / 8);
                N0.q[0] = __hip_atomic_load(sp + rdo * 2,          __ATOMIC_RELAXED, __HIP_MEMORY_SCOPE_AGENT);
                N0.q[1] = __hip_atomic_load(sp + rdo * 2 + 1,      __ATOMIC_RELAXED, __HIP_MEMORY_SCOPE_AGENT);
                N1.q[0] = __hip_atomic_load(sp + (64+rdo) * 2,     __ATOMIC_RELAXED, __HIP_MEMORY_SCOPE_AGENT);
                N1.q[1] = __hip_atomic_load(sp + (64+rdo) * 2 + 1, __ATOMIC_RELAXED, __HIP_MEMORY_SCOPE_AGENT);
            }
            const f16x8* h2o = hf[t & 1];
            f16x8*       h2n = (f16x8*)hf[1 - (t & 1)];
            const f16x8 sb0 = h2o[rdo];
            const f16x8 sb1 = h2o[64 + rdo];
#pragma unroll
            for (int s = 0; s < 2; ++s) if (s < nB) {
                f32x4 aa, ab;
                aa = __builtin_amdgcn_mfma_f32_16x16x32_f16(wI1[s][0], P0.h, z4, 0, 0, 0);
                aa = __builtin_amdgcn_mfma_f32_16x16x32_f16(wI1[s][1], P1.h, aa, 0, 0, 0);
                ab = __builtin_amdgcn_mfma_f32_16x16x32_f16(wH1[s][0], sb0, z4, 0, 0, 0);
                ab = __builtin_amdgcn_mfma_f32_16x16x32_f16(wH1[s][1], sb1, ab, 0, 0, 0);
                const f32x4 acc = aa + ab;
                ((_Float16*)h2n)[wOff[s]] = (_Float16)lstm_cell(acc, c2[s]);
            }
            __syncthreads();
            if (tid == 0)
                __hip_atomic_store(fB, t + 1, __ATOMIC_RELEASE,
                                   __HIP_MEMORY_SCOPE_AGENT);
            P0 = N0;
            P1 = N1;
        }

        // FC head: h2[511] lives in hf[0] (t=511 wrote hf[1-(511&1)] = hf[0])
        if (tid < NB) {
            const int m = tid;
            const _Float16* h2e = (const _Float16*)hf[0];
            float s = fc_b[0];
            for (int j = 0; j < HID; ++j) {
                const int chunk = (((j >> 5) * 4) + ((j >> 3) & 3)) * 16 + m;
                s += fc_w[j] * (float)h2e[chunk * 8 + (j & 7)];
            }
            out[b0 + m] = s;
        }
    }
}

extern "C" void kernel_launch(void* const* d_in, const int* in_sizes, int n_in,
                              void* d_out, int out_size, void* d_ws, size_t ws_size,
                              hipStream_t stream) {
    const float* x     = (const float*)d_in[0];
    const float* w_ih0 = (const float*)d_in[1];
    const float* w_hh0 = (const float*)d_in[2];
    const float* b_ih0 = (const float*)d_in[3];
    const float* b_hh0 = (const float*)d_in[4];
    const float* w_ih1 = (const float*)d_in[5];
    const float* w_hh1 = (const float*)d_in[6];
    const float* b_ih1 = (const float*)d_in[7];
    const float* b_hh1 = (const float*)d_in[8];
    const float* fc_w  = (const float*)d_in[9];
    const float* fc_b  = (const float*)d_in[10];
    float* out = (float*)d_out;

    const int B = in_sizes[0] / SEQ;  // 4096

    // flags use completed-count semantics: zeroed flags = clean start.
    hipMemsetAsync(d_ws, 0, WS_BYTES, stream);

    lstm2_fc_v19<<<2 * (B / NB), NTHREADS, 0, stream>>>(
        x, w_ih0, w_hh0, b_ih0, b_hh0, w_ih1, w_hh1, b_ih1, b_hh1,
        fc_w, fc_b, out, (char*)d_ws);
}

// Round 7
// 383.617 us; speedup vs baseline: 31.0492x; 31.0492x over previous
//
#include <hip/hip_runtime.h>

// 2-layer LSTM (H=50) + FC head. Transposed-MFMA fp16, cross-layer pipelined.
// R20 = REVERT to R13 (measured best: 354 us rocprof / 385 us harness).
// Session map (all falsified, keep for posterity):
//   R14 (-3 trans/cell, longer chain): 363 us -- issue cuts don't move the
//       phase floor; chain depth slightly hurts.
//   R15 (2 blocks/CU, 2x work): 657 us -- co-residency fills bubbles only at
//       81% efficiency; doubled work loses.
//   R16 (8 waves, -45% LDS burst): 406 us -- fewer waves = more exposed seam.
//   R17 (matrix-specialized roles, -21% reads): 356 us -- neutral; LDS burst
//       is not the binding term.
//   R18 (LDS flag sync, decoupled teams): 430 us -- spin + atomic serialization
//       + lost compiler scheduling outweigh desync gains.
//   R19 (split blocks + global ring): 11.9 ms -- agent-scope atomics thrash HBM.
// Work-conservation law (R13/R15/R16): VALU+trans issue = 930 cy/SIMD/phase
// invariant; phase = 930 + exposure(waves); exposure min at 16 waves (727 cy).
// => 1657 cy/phase is this structure's floor. Compute floor ~140 us is locked
// behind the per-step barrier convoy (256 chains / 256 CUs, no spare TLP).
// R13 = R12 + activation scale factors FOLDED INTO THE WEIGHTS:
//   gate rows are pre-scaled at fragment-load: i/f/o rows by -log2e, g rows
//   by +2log2e (including their bias and x K-lane entries), so the MFMA
//   output is directly the exp2 argument: sigmoid = rcp(1+exp2(g)),
//   tanh_gate = 1-2*rcp(1+exp2(g)). Only tanh(c) keeps its scale mul.
// Wave roles (R12): 0..9 dual (L1 tile w + L2 tile w, prio 1), 10..12 L1
// single (12 feeds x), 13..15 L2 single (tiles 10..12).
// Core: gates^T = W @ h^T; A = weights in regs, B = h in LDS frag layout;
// gate rows permuted p=4j+g -> one lane owns a unit's 4 gates -> cell fully
// in-register; x + biases ride dead K-lanes (h1 k=50: x, k=51: 1.0);
// phase p = L1[p] + L2[p-1], ONE barrier/phase (513 = minimum).
// Lessons: NB=16/grid=256 locked (R8); max waves > fat waves (R10); no
// VGPR-squeezing launch_bounds (R3).

#define HID 50
#define SEQ 512
#define NB 16
#define NTHREADS 1024
#define XP 516            // xs row stride (floats)

typedef _Float16 f16x8 __attribute__((ext_vector_type(8)));
typedef float    f32x4 __attribute__((ext_vector_type(4)));

#define LOG2E 1.44269504f

// pre-scaled activations: input is already  -x*log2e  (sig) or  2x*log2e (tanh)
__device__ __forceinline__ float sig_pre(float y) {
    return __builtin_amdgcn_rcpf(1.0f + __builtin_amdgcn_exp2f(y));
}
__device__ __forceinline__ float tanh_pre(float y) {
    return 1.0f - 2.0f * __builtin_amdgcn_rcpf(1.0f + __builtin_amdgcn_exp2f(y));
}
// c is unscaled -> needs the mul
__device__ __forceinline__ float tanh_c(float x) {
    return 1.0f - 2.0f * __builtin_amdgcn_rcpf(
        1.0f + __builtin_amdgcn_exp2f(x * (2.0f * LOG2E)));
}
__device__ __forceinline__ float lstm_cell(const f32x4 g, float& c) {
    const float ii = sig_pre(g[0]);
    const float ff = sig_pre(g[1]);
    const float gg = tanh_pre(g[2]);
    const float oo = sig_pre(g[3]);
    c = ff * c + ii * gg;
    return oo * tanh_c(c);
}

// h LDS layout: 16B chunk (kt*4+qh)*16 + m holds h[m][k = kt*32+qh*8+0..7].
// Reader (lane m=l15, quad qq, k-chunk kt) reads chunk (kt*4+qq)*16+m.
// Writer of h[m][j]: chunk ((j>>5)*4+((j>>3)&3))*16 + m, half j&7.
// j=50 -> chunk 96+m half 2 (x rides here), j=51 -> chunk 96+m half 3 (1.0).

__global__ __launch_bounds__(NTHREADS)
void lstm2_fc_v20(const float* __restrict__ x,
                  const float* __restrict__ w_ih0,
                  const float* __restrict__ w_hh0,
                  const float* __restrict__ b_ih0,
                  const float* __restrict__ b_hh0,
                  const float* __restrict__ w_ih1,
                  const float* __restrict__ w_hh1,
                  const float* __restrict__ b_ih1,
                  const float* __restrict__ b_hh1,
                  const float* __restrict__ fc_w,
                  const float* __restrict__ fc_b,
                  float* __restrict__ out)
{
    __shared__ float xs[NB * XP];        // 33 KB  x for all 512 steps
    __shared__ f16x8 h1f[2][128];        //  4 KB  h1 double-buffered, frag layout
    __shared__ f16x8 h2f[2][128];        //  4 KB  h2 double-buffered

    const int tid = threadIdx.x;
    const int b0  = blockIdx.x * NB;
    const int w   = tid >> 6;            // wave id 0..15
    const int l15 = tid & 15;            // MFMA lane column (batch m)
    const int qq  = (tid >> 4) & 3;      // MFMA lane quad

    // ---- role assignment (wave-uniform) ----
    const bool dual  = (w <= 9);
    const bool hasL1 = (w <= 12);
    const bool hasL2 = dual || (w >= 13);
    const int  tL1   = w;                        // L1 tile (if hasL1)
    const int  tL2   = dual ? w : (w - 3);       // L2 tile (if hasL2)

    if (dual) __builtin_amdgcn_s_setprio(1);     // pacers issue first post-barrier

    // ---- stage x into LDS (coalesced float4) ----
    for (int idx = tid; idx < NB * 128; idx += NTHREADS) {
        const int b  = idx >> 7;
        const int t4 = idx & 127;
        *(float4*)&xs[b * XP + t4 * 4] =
            *(const float4*)&x[(size_t)(b0 + b) * SEQ + t4 * 4];
    }
    if (tid < NB) {                       // zero x pad column t=512..515
        const float4 z = {0.f, 0.f, 0.f, 0.f};
        *(float4*)&xs[tid * XP + 512] = z;
    }
    // ---- zero h buffers ----
    if (tid < 256) {
        f16x8 z = {};
        h1f[tid >> 7][tid & 127] = z;
        h2f[tid >> 7][tid & 127] = z;
    }

    // ---- load weight A-fragments (one-time), gate rows permuted + SCALED ----
    // lane holds W[p = T*16 + l15][k = kt*32 + qq*8 + j], n(p)=(p&3)*HID+(p>>2)
    // row scale: gate (p&3)==2 (tanh) -> +2log2e, else (sigmoid) -> -log2e.
    // L1 frag (w_hh0): specials k=50 -> w_ih0, k=51 -> biasL1 (both scaled).
    // L2 frags: w_ih1 (special k=51 -> biasL2, scaled) and w_hh1.
    f16x8 wH0[2], wI1[2], wH1[2];
    {
        const int  p1  = tL1 * 16 + l15;
        const bool ok1 = hasL1 && (p1 < 4 * HID);
        const int  n1  = ok1 ? ((p1 & 3) * HID + (p1 >> 2)) : 0;
        const float s1 = ((p1 & 3) == 2) ? (2.0f * LOG2E) : -LOG2E;
        const int  p2  = tL2 * 16 + l15;
        const bool ok2 = hasL2 && (p2 < 4 * HID);
        const int  n2  = ok2 ? ((p2 & 3) * HID + (p2 >> 2)) : 0;
        const float s2 = ((p2 & 3) == 2) ? (2.0f * LOG2E) : -LOG2E;
#pragma unroll
        for (int kt = 0; kt < 2; ++kt) {
            f16x8 f0, f1, f2;
#pragma unroll
            for (int j = 0; j < 8; ++j) {
                const int k = kt * 32 + qq * 8 + j;
                float v0 = 0.0f, v1 = 0.0f, v2 = 0.0f;
                if (ok1) {
                    if (k < HID)          v0 = w_hh0[n1 * HID + k];
                    else if (k == HID)    v0 = w_ih0[n1];
                    else if (k == HID+1)  v0 = b_ih0[n1] + b_hh0[n1];
                    v0 *= s1;
                }
                if (ok2) {
                    if (k < HID)        { v1 = w_ih1[n2 * HID + k];
                                          v2 = w_hh1[n2 * HID + k]; }
                    else if (k == HID+1)  v1 = b_ih1[n2] + b_hh1[n2];
                    v1 *= s2;
                    v2 *= s2;
                }
                f0[j] = (_Float16)v0;
                f1[j] = (_Float16)v1;
                f2[j] = (_Float16)v2;
            }
            wH0[kt] = f0;
            wI1[kt] = f1;
            wH1[kt] = f2;
        }
    }

    // ---- per-lane invariants ----
    const int juL1   = tL1 * 4 + qq;             // unit of my L1 tile (<=51)
    const int juL2   = tL2 * 4 + qq;
    const int wOffL1 = ((((juL1 >> 5) * 4) + ((juL1 >> 3) & 3)) * 16 + l15) * 8 + (juL1 & 7);
    const int wOffL2 = ((((juL2 >> 5) * 4) + ((juL2 >> 3) & 3)) * 16 + l15) * 8 + (juL2 & 7);
    const int rdo = qq * 16 + l15;               // B-frag chunk index, kt=0
    const float* xrow = xs + l15 * XP;           // x row (wave 12, qq==2 feeds x)
    const f32x4 z4 = {0.f, 0.f, 0.f, 0.f};       // hoisted zero accumulator

    float c1 = 0.f, c2 = 0.f;

    __syncthreads();   // xs + zeros visible

    // ---- seed specials: h1f[0] k=50 = x[m][0]; k=51 = 1.0 in BOTH buffers.
    // The 1.0 lane (wave 12 qq=3) never writes in-loop, so both stay valid.
    if (tid < NB) {
        _Float16* e0 = (_Float16*)&h1f[0][96 + tid];
        e0[2] = (_Float16)xs[tid * XP];
        e0[3] = (_Float16)1.0f;
        ((_Float16*)&h1f[1][96 + tid])[3] = (_Float16)1.0f;
    }
    __syncthreads();

    // ---- phase body: L1-part [p], L2-part [p-1]; one barrier ----
    auto phase = [&](const f16x8* __restrict__ h1o, const f16x8* __restrict__ h2o,
                     f16x8* __restrict__ h1n, f16x8* __restrict__ h2n,
                     int p, bool doL1, bool doL2) {
        const f16x8 hb0 = h1o[rdo];              // shared by L1 and L2 parts
        const f16x8 hb1 = h1o[64 + rdo];
        if (hasL2 && doL2) {
            const f16x8 sb0 = h2o[rdo];
            const f16x8 sb1 = h2o[64 + rdo];
            f32x4 acc;
            acc = __builtin_amdgcn_mfma_f32_16x16x32_f16(wI1[0], hb0, z4,  0, 0, 0);
            acc = __builtin_amdgcn_mfma_f32_16x16x32_f16(wI1[1], hb1, acc, 0, 0, 0);
            acc = __builtin_amdgcn_mfma_f32_16x16x32_f16(wH1[0], sb0, acc, 0, 0, 0);
            acc = __builtin_amdgcn_mfma_f32_16x16x32_f16(wH1[1], sb1, acc, 0, 0, 0);
            ((_Float16*)h2n)[wOffL2] = (_Float16)lstm_cell(acc, c2);
        }
        if (hasL1 && doL1) {
            f32x4 acc;
            acc = __builtin_amdgcn_mfma_f32_16x16x32_f16(wH0[0], hb0, z4,  0, 0, 0);
            acc = __builtin_amdgcn_mfma_f32_16x16x32_f16(wH0[1], hb1, acc, 0, 0, 0);
            const _Float16 hw = (_Float16)lstm_cell(acc, c1);
            if (w < 12) {                          // wave-uniform
                ((_Float16*)h1n)[wOffL1] = hw;
            } else {                               // wave 12: units 48..51
                if (qq < 2)       ((_Float16*)h1n)[wOffL1] = hw;
                else if (qq == 2) ((_Float16*)h1n)[wOffL1] =
                                      (_Float16)xrow[p + 1];
                /* qq == 3: the 1.0 lane, pre-seeded, never written */
            }
        }
        __syncthreads();
    };

    // phase p reads buf[p&1], writes buf[1-(p&1)]
    phase(h1f[0], h2f[0], h1f[1], h2f[1], 0, true, false);      // L1[0]
#pragma unroll 1
    for (int p = 1; p <= 509; p += 2) {
        phase(h1f[1], h2f[1], h1f[0], h2f[0], p,     true, true);
        phase(h1f[0], h2f[0], h1f[1], h2f[1], p + 1, true, true);
    }
    phase(h1f[1], h2f[1], h1f[0], h2f[0], 511, true,  true);
    phase(h1f[0], h2f[0], h1f[1], h2f[1], 512, false, true);    // L2[511]
    // h2[511] now lives in h2f[1]

    // ============ FC head: out[b] = h2[T-1] . fc_w + fc_b ============
    if (tid < NB) {
        const int m = tid;
        const _Float16* h2e = (const _Float16*)h2f[1];
        float s = fc_b[0];
        for (int j = 0; j < HID; ++j) {
            const int chunk = (((j >> 5) * 4) + ((j >> 3) & 3)) * 16 + m;
            s += fc_w[j] * (float)h2e[chunk * 8 + (j & 7)];
        }
        out[b0 + m] = s;
    }
}

extern "C" void kernel_launch(void* const* d_in, const int* in_sizes, int n_in,
                              void* d_out, int out_size, void* d_ws, size_t ws_size,
                              hipStream_t stream) {
    const float* x     = (const float*)d_in[0];
    const float* w_ih0 = (const float*)d_in[1];
    const float* w_hh0 = (const float*)d_in[2];
    const float* b_ih0 = (const float*)d_in[3];
    const float* b_hh0 = (const float*)d_in[4];
    const float* w_ih1 = (const float*)d_in[5];
    const float* w_hh1 = (const float*)d_in[6];
    const float* b_ih1 = (const float*)d_in[7];
    const float* b_hh1 = (const float*)d_in[8];
    const float* fc_w  = (const float*)d_in[9];
    const float* fc_b  = (const float*)d_in[10];
    float* out = (float*)d_out;

    const int B = in_sizes[0] / SEQ;  // 4096

    lstm2_fc_v20<<<B / NB, NTHREADS, 0, stream>>>(
        x, w_ih0, w_hh0, b_ih0, b_hh0, w_ih1, w_hh1, b_ih1, b_hh1, fc_w, fc_b, out);
}